// Round 1
// baseline (570.191 us; speedup 1.0000x reference)
//
#include <hip/hip_runtime.h>
#include <cstddef>

// CAM module, algebraically restructured:
//   X = concat(rgb,hsv,lab) : [B=4, 192, N=65536] (f32)
//   G[b] = X X^T (192x192), s[b] = row sums        (K1, fp16 MFMA + f32 sums)
//   energy = (Wq G Wk^T + bq sk^T + sq bk^T + N bq bk^T)/8 ; att = softmax_d
//   M = att Wv ; c0 = att bv                        (K2, f32)
//   out = M X + c0                                  (K3, f32 VALU)

#define NPIX 65536

typedef _Float16 half4_t __attribute__((ext_vector_type(4)));
typedef _Float16 half8_t __attribute__((ext_vector_type(8)));
typedef float f32x4_t __attribute__((ext_vector_type(4)));

// triangle (I<=J) enumeration of the 12x12 grid of 16x16 tiles over 192x192
constexpr int TRI_I[78] = {
  0,0,0,0,0,0,0,0,0,0,0,0,
  1,1,1,1,1,1,1,1,1,1,1,
  2,2,2,2,2,2,2,2,2,2,
  3,3,3,3,3,3,3,3,3,
  4,4,4,4,4,4,4,4,
  5,5,5,5,5,5,5,
  6,6,6,6,6,6,
  7,7,7,7,7,
  8,8,8,8,
  9,9,9,
  10,10,
  11};
constexpr int TRI_J[78] = {
  0,1,2,3,4,5,6,7,8,9,10,11,
  1,2,3,4,5,6,7,8,9,10,11,
  2,3,4,5,6,7,8,9,10,11,
  3,4,5,6,7,8,9,10,11,
  4,5,6,7,8,9,10,11,
  5,6,7,8,9,10,11,
  6,7,8,9,10,11,
  7,8,9,10,11,
  8,9,10,11,
  9,10,11,
  10,11,
  11};

__global__ void k0_zero(float* __restrict__ p, int n) {
  int i = blockIdx.x * 256 + threadIdx.x;
  if (i < n) p[i] = 0.0f;
}

template <int W>
__device__ __forceinline__ void mfma_tiles(const half8_t* fr, f32x4_t* acc) {
  constexpr int nt = (78 - W + 7) / 8;
#pragma unroll
  for (int tt = 0; tt < nt; ++tt) {
    const int t = W + 8 * tt;  // folds to literal after unroll
    acc[tt] = __builtin_amdgcn_mfma_f32_16x16x32_f16(fr[TRI_I[t]], fr[TRI_J[t]], acc[tt], 0, 0, 0);
  }
}

template <int W>
__device__ __forceinline__ void flush_part(const f32x4_t* acc, float* __restrict__ pb, int lane) {
  constexpr int nt = (78 - W + 7) / 8;
#pragma unroll
  for (int tt = 0; tt < nt; ++tt) {
    const int t = W + 8 * tt;
    *(f32x4_t*)(pb + t * 256 + lane * 4) = acc[tt];
  }
}

template <int W>
__device__ __forceinline__ void flush_atomic(const f32x4_t* acc, float* __restrict__ Gb, int lane) {
  constexpr int nt = (78 - W + 7) / 8;
#pragma unroll
  for (int tt = 0; tt < nt; ++tt) {
    const int t = W + 8 * tt;
    const int I = TRI_I[t], J = TRI_J[t];
#pragma unroll
    for (int r = 0; r < 4; ++r) {
      int row = I * 16 + ((lane >> 4) << 2) + r;  // C layout: row=(lane>>4)*4+reg
      int col = J * 16 + (lane & 15);             //           col=lane&15
      atomicAdd(Gb + row * 192 + col, acc[tt][r]);
    }
  }
}

// K1: per-block 1024 columns of one batch; Gram accumulated in registers across
// 16 chunks of 64 cols; LDS fp16 tile [192][64] with XOR swizzle (col^=(row&7)<<3).
__global__ __launch_bounds__(512, 2) void k1_gram(
    const float* __restrict__ rgb, const float* __restrict__ hsv, const float* __restrict__ lab,
    float* __restrict__ G, float* __restrict__ S, float* __restrict__ part, int use_part) {
  __shared__ alignas(16) _Float16 lds[12288];
  const int t = threadIdx.x;
  const int lane = t & 63;
  const int w = t >> 6;
  const int b = blockIdx.y;
  const int n0 = blockIdx.x * 1024;
  const float* srcs[3] = {rgb, hsv, lab};

  f32x4_t acc[10];
  const f32x4_t zero4 = {0.0f, 0.0f, 0.0f, 0.0f};
#pragma unroll
  for (int i = 0; i < 10; ++i) acc[i] = zero4;
  float s_acc[6] = {0.f, 0.f, 0.f, 0.f, 0.f, 0.f};

  const int sub = t >> 4;        // 0..31 (row within 32-row group)
  const int c4 = (t & 15) * 4;   // 0..60 (col within chunk)

  size_t base[6];
#pragma unroll
  for (int p = 0; p < 6; ++p) {
    int row = 32 * p + sub;
    base[p] = (size_t)(b * 64 + (row & 63)) * NPIX + n0 + c4;
  }
  float4 reg[6];
#pragma unroll
  for (int p = 0; p < 6; ++p) reg[p] = *(const float4*)(srcs[p >> 1] + base[p]);

  for (int cc = 0; cc < 16; ++cc) {
#pragma unroll
    for (int p = 0; p < 6; ++p) {
      float4 x = reg[p];
      s_acc[p] += x.x + x.y + x.z + x.w;
      int row = 32 * p + sub;
      int idx = row * 64 + (c4 ^ ((row & 7) << 3));
      half4_t h;
      h.x = (_Float16)x.x; h.y = (_Float16)x.y; h.z = (_Float16)x.z; h.w = (_Float16)x.w;
      *(half4_t*)(lds + idx) = h;
    }
    __syncthreads();
    if (cc + 1 < 16) {
#pragma unroll
      for (int p = 0; p < 6; ++p) reg[p] = *(const float4*)(srcs[p >> 1] + base[p] + (cc + 1) * 64);
    }
#pragma unroll
    for (int ks = 0; ks < 2; ++ks) {
      half8_t fr[12];
      const int kc = ks * 32 + 8 * (lane >> 4);
#pragma unroll
      for (int r = 0; r < 12; ++r) {
        int row = r * 16 + (lane & 15);
        fr[r] = *(const half8_t*)(lds + row * 64 + (kc ^ ((row & 7) << 3)));
      }
      switch (w) {
        case 0: mfma_tiles<0>(fr, acc); break;
        case 1: mfma_tiles<1>(fr, acc); break;
        case 2: mfma_tiles<2>(fr, acc); break;
        case 3: mfma_tiles<3>(fr, acc); break;
        case 4: mfma_tiles<4>(fr, acc); break;
        case 5: mfma_tiles<5>(fr, acc); break;
        case 6: mfma_tiles<6>(fr, acc); break;
        case 7: mfma_tiles<7>(fr, acc); break;
      }
    }
    __syncthreads();
  }

  if (use_part) {
    float* pb = part + (size_t)(b * 64 + blockIdx.x) * 19968;
    switch (w) {
      case 0: flush_part<0>(acc, pb, lane); break;
      case 1: flush_part<1>(acc, pb, lane); break;
      case 2: flush_part<2>(acc, pb, lane); break;
      case 3: flush_part<3>(acc, pb, lane); break;
      case 4: flush_part<4>(acc, pb, lane); break;
      case 5: flush_part<5>(acc, pb, lane); break;
      case 6: flush_part<6>(acc, pb, lane); break;
      case 7: flush_part<7>(acc, pb, lane); break;
    }
  } else {
    float* Gb = G + b * 36864;
    switch (w) {
      case 0: flush_atomic<0>(acc, Gb, lane); break;
      case 1: flush_atomic<1>(acc, Gb, lane); break;
      case 2: flush_atomic<2>(acc, Gb, lane); break;
      case 3: flush_atomic<3>(acc, Gb, lane); break;
      case 4: flush_atomic<4>(acc, Gb, lane); break;
      case 5: flush_atomic<5>(acc, Gb, lane); break;
      case 6: flush_atomic<6>(acc, Gb, lane); break;
      case 7: flush_atomic<7>(acc, Gb, lane); break;
    }
  }
#pragma unroll
  for (int p = 0; p < 6; ++p) atomicAdd(S + b * 192 + 32 * p + sub, s_acc[p]);
}

// K1.5a: deterministic reduction of 64 partial Grams per batch + mirror to full G.
__global__ void k1r_reduce(const float* __restrict__ part, float* __restrict__ G) {
  int idx = blockIdx.x * 256 + threadIdx.x;
  if (idx >= 4 * 19968) return;
  int b = idx / 19968;
  int flat = idx % 19968;
  const float* p = part + (size_t)b * 64 * 19968 + flat;
  float v = 0.f;
  for (int q = 0; q < 64; ++q) v += p[(size_t)q * 19968];
  int tt = flat >> 8;
  int r = flat & 255;
  int lane = r >> 2, rg = r & 3;
  int I = 0, rem = tt;
  while (rem >= 12 - I) { rem -= 12 - I; ++I; }
  int J = I + rem;
  int row = I * 16 + ((lane >> 4) << 2) + rg;
  int col = J * 16 + (lane & 15);
  float* Gb = G + b * 36864;
  Gb[row * 192 + col] = v;
  Gb[col * 192 + row] = v;
}

// K1.5b (atomic fallback path): mirror lower block-triangle from upper.
__global__ void k1m_mirror(float* __restrict__ G) {
  int b = blockIdx.y;
  int idx = blockIdx.x * 256 + threadIdx.x;
  int i = idx / 192, j = idx % 192;
  if ((i >> 4) > (j >> 4)) G[b * 36864 + idx] = G[b * 36864 + j * 192 + i];
}

// K2: energy -> softmax -> M, c0.  grid (8 c-blocks, 4 b), 256 thr.
__global__ __launch_bounds__(256) void k2_small(
    const float* __restrict__ G, const float* __restrict__ S,
    const float* __restrict__ Wq, const float* __restrict__ bq,
    const float* __restrict__ Wk, const float* __restrict__ bk,
    const float* __restrict__ Wv, const float* __restrict__ bv,
    float* __restrict__ Mw, float* __restrict__ c0w) {
  const int b = blockIdx.y;
  const int cbase = blockIdx.x * 8;
  const int t = threadIdx.x;
  __shared__ float T1[192 * 9];  // T1^T[j][c'] pitch 9 (conflict-free)
  __shared__ float el[64 * 8];   // e[d][c']
  __shared__ float sq[8];
  __shared__ float sk[64];
  const float* Gb = G + b * 36864;
  const float* Sb = S + b * 192;

  if (t < 8) {
    float a = 0.f;
    const float* wq = Wq + (cbase + t) * 192;
    for (int i = 0; i < 192; ++i) a = fmaf(wq[i], Sb[i], a);
    sq[t] = a;
  } else if (t < 72) {
    int d = t - 8;
    float a = 0.f;
    const float* wk = Wk + d * 192;
    for (int j = 0; j < 192; ++j) a = fmaf(wk[j], Sb[j], a);
    sk[d] = a;
  }
  for (int e = t; e < 1536; e += 256) {
    int j = e % 192, cp = e / 192;
    const float* wq = Wq + (cbase + cp) * 192;
    float a = 0.f;
    for (int i = 0; i < 192; ++i) a = fmaf(wq[i], Gb[i * 192 + j], a);
    T1[j * 9 + cp] = a;
  }
  __syncthreads();
  for (int e = t; e < 512; e += 256) {
    int cp = e & 7, d = e >> 3;
    const float* wk = Wk + d * 192;
    float a = 0.f;
    for (int j = 0; j < 192; ++j) a = fmaf(T1[j * 9 + cp], wk[j], a);
    float bqc = bq[cbase + cp], bkd = bk[d];
    a += bqc * sk[d] + bkd * sq[cp] + 65536.0f * bqc * bkd;
    el[d * 8 + cp] = a * 0.125f;  // * C^-0.5
  }
  __syncthreads();
  if (t < 8) {  // softmax over d for each of this block's 8 rows
    float mx = -3.0e38f;
    for (int d = 0; d < 64; ++d) mx = fmaxf(mx, el[d * 8 + t]);
    float sum = 0.f;
    for (int d = 0; d < 64; ++d) {
      float pv = expf(el[d * 8 + t] - mx);
      el[d * 8 + t] = pv;
      sum += pv;
    }
    float inv = 1.0f / sum;
    for (int d = 0; d < 64; ++d) el[d * 8 + t] *= inv;
  }
  __syncthreads();
  for (int e = t; e < 1536; e += 256) {
    int i = e % 192, cp = e / 192;
    float a = 0.f;
    for (int d = 0; d < 64; ++d) a = fmaf(el[d * 8 + cp], Wv[d * 192 + i], a);
    Mw[b * 12288 + (cbase + cp) * 192 + i] = a;
  }
  if (t < 8) {
    float a = 0.f;
    for (int d = 0; d < 64; ++d) a = fmaf(el[d * 8 + t], bv[d], a);
    c0w[b * 64 + cbase + t] = a;
  }
}

// K3: out[b,c,n] = sum_i M[b,c,i] X[b,i,n] + c0[b,c].  f32 VALU, M broadcast
// from LDS, 2 columns per thread.
__global__ __launch_bounds__(256, 2) void k3_out(
    const float* __restrict__ rgb, const float* __restrict__ hsv, const float* __restrict__ lab,
    const float* __restrict__ Mw, const float* __restrict__ c0w, float* __restrict__ out) {
  __shared__ alignas(16) float Ml[12288];
  __shared__ float c0l[64];
  const int b = blockIdx.y;
  const int t = threadIdx.x;
  const int n = blockIdx.x * 512 + 2 * t;
  for (int k = t; k < 12288; k += 256) Ml[k] = Mw[b * 12288 + k];
  if (t < 64) c0l[t] = c0w[b * 64 + t];
  __syncthreads();
  float2 acc[64];
#pragma unroll
  for (int c = 0; c < 64; ++c) { acc[c].x = 0.f; acc[c].y = 0.f; }
  for (int i0 = 0; i0 < 192; i0 += 4) {
    const float* src = (i0 < 64) ? rgb : (i0 < 128) ? hsv : lab;
    const float* p = src + (size_t)(b * 64 + (i0 & 63)) * NPIX + n;
    float2 x0 = *(const float2*)(p);
    float2 x1 = *(const float2*)(p + NPIX);
    float2 x2 = *(const float2*)(p + 2 * (size_t)NPIX);
    float2 x3 = *(const float2*)(p + 3 * (size_t)NPIX);
#pragma unroll
    for (int c = 0; c < 64; ++c) {
      float4 m = *(const float4*)(Ml + c * 192 + i0);
      acc[c].x = fmaf(m.x, x0.x, fmaf(m.y, x1.x, fmaf(m.z, x2.x, fmaf(m.w, x3.x, acc[c].x))));
      acc[c].y = fmaf(m.x, x0.y, fmaf(m.y, x1.y, fmaf(m.z, x2.y, fmaf(m.w, x3.y, acc[c].y))));
    }
  }
#pragma unroll
  for (int c = 0; c < 64; ++c) {
    float2 o;
    o.x = acc[c].x + c0l[c];
    o.y = acc[c].y + c0l[c];
    *(float2*)(out + (size_t)(b * 64 + c) * NPIX + n) = o;
  }
}

extern "C" void kernel_launch(void* const* d_in, const int* in_sizes, int n_in,
                              void* d_out, int out_size, void* d_ws, size_t ws_size,
                              hipStream_t stream) {
  const float* rgb = (const float*)d_in[0];
  const float* hsv = (const float*)d_in[1];
  const float* lab = (const float*)d_in[2];
  const float* Wq = (const float*)d_in[3];
  const float* bq = (const float*)d_in[4];
  const float* Wk = (const float*)d_in[5];
  const float* bk = (const float*)d_in[6];
  const float* Wv = (const float*)d_in[7];
  const float* bv = (const float*)d_in[8];
  float* out = (float*)d_out;
  float* ws = (float*)d_ws;

  float* G = ws;                  // 4*192*192 = 147456 f32
  float* S = ws + 147456;         // 4*192     = 768
  float* Mw = ws + 148224;        // 4*64*192  = 49152
  float* c0w = ws + 197376;       // 4*64      = 256
  float* part = ws + 197632;      // 256*19968 = 5111808 (optional partials)
  const int use_part = (ws_size >= (size_t)(197632 + 5111808) * sizeof(float)) ? 1 : 0;

  k0_zero<<<dim3(579), dim3(256), 0, stream>>>(ws, 148224);  // zero G + S
  k1_gram<<<dim3(64, 4), dim3(512), 0, stream>>>(rgb, hsv, lab, G, S, part, use_part);
  if (use_part)
    k1r_reduce<<<dim3(312), dim3(256), 0, stream>>>(part, G);
  else
    k1m_mirror<<<dim3(144, 4), dim3(256), 0, stream>>>(G);
  k2_small<<<dim3(8, 4), dim3(256), 0, stream>>>(G, S, Wq, bq, Wk, bk, Wv, bv, Mw, c0w);
  k3_out<<<dim3(128, 4), dim3(256), 0, stream>>>(rgb, hsv, lab, Mw, c0w, out);
}

// Round 2
// 207.270 us; speedup vs baseline: 2.7510x; 2.7510x over previous
//
#include <hip/hip_runtime.h>
#include <cstddef>

// CAM module, algebraically restructured:
//   X = concat(rgb,hsv,lab) : [B=4, 192, N=65536] (f32)
//   G[b] = X X^T (192x192), s[b] = row sums        (K1, fp16 MFMA, full 144-tile grid)
//   energy = (Wq G Wk^T + bq sk^T + sq bk^T + N bq bk^T)/8 ; att = softmax_d
//   M = att Wv ; c0 = att bv                        (K2, f32)
//   out = M X + c0                                  (K3, f32 VALU, wave-owns-channels)

#define NPIX 65536

typedef _Float16 half4_t __attribute__((ext_vector_type(4)));
typedef _Float16 half8_t __attribute__((ext_vector_type(8)));
typedef float f32x4_t __attribute__((ext_vector_type(4)));

// ---------------- K0: zero G+S (atomic-fallback path only) ----------------
__global__ void k0_zero(float* __restrict__ p, int n) {
  int i = blockIdx.x * 256 + threadIdx.x;
  if (i < n) p[i] = 0.0f;
}

// ---------------- K1: Gram + row sums ----------------
// grid (64, 4), block 768 (12 waves as 2x6). Each block: 1024 columns of batch b,
// 16 chunks of 64 cols staged in LDS fp16 with XOR swizzle (0 conflicts measured).
// Wave (wi,wj): row-tiles I = wi*6+a (a<6), col-tiles J = wj*2+jj (jj<2).
// acc[6][2] f32x4 = 48 VGPR; frags 8x half8 = 32 VGPR; prefetch 4x float4 = 16.
__global__ __launch_bounds__(768, 3) void k1_gram(
    const float* __restrict__ rgb, const float* __restrict__ hsv, const float* __restrict__ lab,
    float* __restrict__ G, float* __restrict__ S, float* __restrict__ part, int use_part) {
  __shared__ alignas(16) unsigned char smem[24576];
  _Float16* lds = (_Float16*)smem;
  float* slds = (float*)smem;

  const int t = threadIdx.x;
  const int lane = t & 63;
  const int w = t >> 6;          // 0..11
  const int wi = w & 1;          // 0..1
  const int wj = w >> 1;         // 0..5
  const int b = blockIdx.y;
  const int n0 = blockIdx.x * 1024;

  // staging assignment: thread -> (row = t>>2, 16 cols at cq)
  const int row = t >> 2;        // 0..191
  const int cq = (t & 3) << 4;   // 0,16,32,48
  const float* srcs[3] = {rgb, hsv, lab};
  const float* gp = srcs[row >> 6] + (size_t)(b * 64 + (row & 63)) * NPIX + n0 + cq;

  f32x4_t acc[6][2];
  const f32x4_t zero4 = {0.0f, 0.0f, 0.0f, 0.0f};
#pragma unroll
  for (int a = 0; a < 6; ++a)
#pragma unroll
    for (int j = 0; j < 2; ++j) acc[a][j] = zero4;
  float s_acc = 0.0f;

  float4 r0 = *(const float4*)(gp + 0);
  float4 r1 = *(const float4*)(gp + 4);
  float4 r2 = *(const float4*)(gp + 8);
  float4 r3 = *(const float4*)(gp + 12);

  const int sw = (row & 7) << 3;   // swizzle (fp16 units)
  const int rbase = row * 64;

  for (int cc = 0; cc < 16; ++cc) {
    s_acc += (r0.x + r0.y + r0.z + r0.w) + (r1.x + r1.y + r1.z + r1.w) +
             (r2.x + r2.y + r2.z + r2.w) + (r3.x + r3.y + r3.z + r3.w);
    {
      half4_t h;
      h.x = (_Float16)r0.x; h.y = (_Float16)r0.y; h.z = (_Float16)r0.z; h.w = (_Float16)r0.w;
      *(half4_t*)(lds + rbase + ((cq + 0) ^ sw)) = h;
      h.x = (_Float16)r1.x; h.y = (_Float16)r1.y; h.z = (_Float16)r1.z; h.w = (_Float16)r1.w;
      *(half4_t*)(lds + rbase + ((cq + 4) ^ sw)) = h;
      h.x = (_Float16)r2.x; h.y = (_Float16)r2.y; h.z = (_Float16)r2.z; h.w = (_Float16)r2.w;
      *(half4_t*)(lds + rbase + ((cq + 8) ^ sw)) = h;
      h.x = (_Float16)r3.x; h.y = (_Float16)r3.y; h.z = (_Float16)r3.z; h.w = (_Float16)r3.w;
      *(half4_t*)(lds + rbase + ((cq + 12) ^ sw)) = h;
    }
    __syncthreads();
    if (cc + 1 < 16) {
      const float* gp2 = gp + (cc + 1) * 64;
      r0 = *(const float4*)(gp2 + 0);
      r1 = *(const float4*)(gp2 + 4);
      r2 = *(const float4*)(gp2 + 8);
      r3 = *(const float4*)(gp2 + 12);
    }
#pragma unroll
    for (int ks = 0; ks < 2; ++ks) {
      const int kc = ks * 32 + 8 * (lane >> 4);
      half8_t fA[6], fB[2];
#pragma unroll
      for (int a = 0; a < 6; ++a) {
        int rA = wi * 96 + a * 16 + (lane & 15);
        fA[a] = *(const half8_t*)(lds + rA * 64 + (kc ^ ((rA & 7) << 3)));
      }
#pragma unroll
      for (int j = 0; j < 2; ++j) {
        int rB = (wj * 2 + j) * 16 + (lane & 15);
        fB[j] = *(const half8_t*)(lds + rB * 64 + (kc ^ ((rB & 7) << 3)));
      }
#pragma unroll
      for (int a = 0; a < 6; ++a)
#pragma unroll
        for (int j = 0; j < 2; ++j)
          acc[a][j] = __builtin_amdgcn_mfma_f32_16x16x32_f16(fA[a], fB[j], acc[a][j], 0, 0, 0);
    }
    __syncthreads();
  }

  // ---- flush Gram ----
  if (use_part) {
    float* pb = part + (size_t)(b * 64 + blockIdx.x) * 37056;
#pragma unroll
    for (int a = 0; a < 6; ++a)
#pragma unroll
      for (int j = 0; j < 2; ++j) {
        int tt = (wi * 6 + a) * 12 + (wj * 2 + j);
        *(f32x4_t*)(pb + tt * 256 + lane * 4) = acc[a][j];
      }
  } else {
    float* Gb = G + b * 36864;
#pragma unroll
    for (int a = 0; a < 6; ++a)
#pragma unroll
      for (int j = 0; j < 2; ++j) {
        int I = wi * 6 + a, J = wj * 2 + j;
#pragma unroll
        for (int r = 0; r < 4; ++r) {
          int gr = I * 16 + ((lane >> 4) << 2) + r;  // C layout: row=(lane>>4)*4+reg
          int gc = J * 16 + (lane & 15);             //           col=lane&15
          atomicAdd(Gb + gr * 192 + gc, acc[a][j][r]);
        }
      }
  }

  // ---- row sums (reuse LDS as f32) ----
  slds[t] = s_acc;
  __syncthreads();
  if (t < 192) {
    float s = (slds[t * 4] + slds[t * 4 + 1]) + (slds[t * 4 + 2] + slds[t * 4 + 3]);
    if (use_part)
      part[(size_t)(b * 64 + blockIdx.x) * 37056 + 36864 + t] = s;
    else
      atomicAdd(S + b * 192 + t, s);
  }
}

// ---------------- K1.5: deterministic reduce of 64 partials ----------------
__global__ void k1r_reduce(const float* __restrict__ part, float* __restrict__ G,
                           float* __restrict__ S) {
  int idx = blockIdx.x * 256 + threadIdx.x;
  if (idx >= 4 * 37056) return;
  int b = idx / 37056;
  int flat = idx % 37056;
  const float* base = part + (size_t)b * 64 * 37056 + flat;
  float v0 = 0.f, v1 = 0.f, v2 = 0.f, v3 = 0.f;
#pragma unroll
  for (int q = 0; q < 64; q += 4) {
    v0 += base[(size_t)(q + 0) * 37056];
    v1 += base[(size_t)(q + 1) * 37056];
    v2 += base[(size_t)(q + 2) * 37056];
    v3 += base[(size_t)(q + 3) * 37056];
  }
  float v = (v0 + v1) + (v2 + v3);
  if (flat < 36864) {
    int tt = flat >> 8;
    int I = tt / 12, J = tt % 12;
    int r = flat & 255;
    int lane = r >> 2, rg = r & 3;
    int row = I * 16 + ((lane >> 4) << 2) + rg;
    int col = J * 16 + (lane & 15);
    G[b * 36864 + row * 192 + col] = v;
  } else {
    S[b * 192 + (flat - 36864)] = v;
  }
}

// ---------------- K2: energy -> softmax -> M, c0 ----------------
__global__ __launch_bounds__(256) void k2_small(
    const float* __restrict__ G, const float* __restrict__ S,
    const float* __restrict__ Wq, const float* __restrict__ bq,
    const float* __restrict__ Wk, const float* __restrict__ bk,
    const float* __restrict__ Wv, const float* __restrict__ bv,
    float* __restrict__ Mw, float* __restrict__ c0w) {
  const int b = blockIdx.y;
  const int cbase = blockIdx.x * 8;
  const int t = threadIdx.x;
  __shared__ float T1[192 * 9];  // T1^T[j][c'] pitch 9
  __shared__ float el[64 * 8];   // e[d][c']
  __shared__ float sq[8];
  __shared__ float sk[64];
  const float* Gb = G + b * 36864;
  const float* Sb = S + b * 192;

  if (t < 8) {
    float a = 0.f;
    const float* wq = Wq + (cbase + t) * 192;
    for (int i = 0; i < 192; ++i) a = fmaf(wq[i], Sb[i], a);
    sq[t] = a;
  } else if (t < 72) {
    int d = t - 8;
    float a = 0.f;
    const float* wk = Wk + d * 192;
    for (int j = 0; j < 192; ++j) a = fmaf(wk[j], Sb[j], a);
    sk[d] = a;
  }
  for (int e = t; e < 1536; e += 256) {
    int j = e % 192, cp = e / 192;
    const float* wq = Wq + (cbase + cp) * 192;
    float a = 0.f;
    for (int i = 0; i < 192; ++i) a = fmaf(wq[i], Gb[i * 192 + j], a);
    T1[j * 9 + cp] = a;
  }
  __syncthreads();
  for (int e = t; e < 512; e += 256) {
    int cp = e & 7, d = e >> 3;
    const float* wk = Wk + d * 192;
    float a = 0.f;
    for (int j = 0; j < 192; ++j) a = fmaf(T1[j * 9 + cp], wk[j], a);
    float bqc = bq[cbase + cp], bkd = bk[d];
    a += bqc * sk[d] + bkd * sq[cp] + 65536.0f * bqc * bkd;
    el[d * 8 + cp] = a * 0.125f;  // * C^-0.5
  }
  __syncthreads();
  if (t < 8) {
    float mx = -3.0e38f;
    for (int d = 0; d < 64; ++d) mx = fmaxf(mx, el[d * 8 + t]);
    float sum = 0.f;
    for (int d = 0; d < 64; ++d) {
      float pv = expf(el[d * 8 + t] - mx);
      el[d * 8 + t] = pv;
      sum += pv;
    }
    float inv = 1.0f / sum;
    for (int d = 0; d < 64; ++d) el[d * 8 + t] *= inv;
  }
  __syncthreads();
  for (int e = t; e < 1536; e += 256) {
    int i = e % 192, cp = e / 192;
    float a = 0.f;
    for (int d = 0; d < 64; ++d) a = fmaf(el[d * 8 + cp], Wv[d * 192 + i], a);
    Mw[b * 12288 + (cbase + cp) * 192 + i] = a;
  }
  if (t < 8) {
    float a = 0.f;
    for (int d = 0; d < 64; ++d) a = fmaf(el[d * 8 + t], bv[d], a);
    c0w[b * 64 + cbase + t] = a;
  }
}

// ---------------- K3: out = M X + c0 ----------------
// grid (256, 4), block 512 (8 waves). Wave w owns channels w*8..w*8+7; lane owns
// 4 cols. x staged per 4-row step in LDS (conflict-free); M reads are broadcast.
// acc = 8 x float4 = 32 VGPR.
__global__ __launch_bounds__(512, 4) void k3_out(
    const float* __restrict__ rgb, const float* __restrict__ hsv, const float* __restrict__ lab,
    const float* __restrict__ Mw, const float* __restrict__ c0w, float* __restrict__ out) {
  __shared__ alignas(16) float Ml[12288];
  __shared__ float c0l[64];
  __shared__ alignas(16) float xl[4 * 256];
  const int b = blockIdx.y;
  const int t = threadIdx.x;
  const int lane = t & 63;
  const int w = t >> 6;
  const int n0 = blockIdx.x * 256;

  for (int k = t; k < 12288; k += 512) Ml[k] = Mw[b * 12288 + k];
  if (t < 64) c0l[t] = c0w[b * 64 + t];

  const int xr_row = t >> 7;          // 0..3
  const int xr_col = (t & 127) * 2;   // 0..254
  const float* srcs[3] = {rgb, hsv, lab};

  float2 xr = *(const float2*)(srcs[0] + (size_t)(b * 64 + xr_row) * NPIX + n0 + xr_col);

  float4 acc[8];
#pragma unroll
  for (int c = 0; c < 8; ++c) { acc[c].x = 0.f; acc[c].y = 0.f; acc[c].z = 0.f; acc[c].w = 0.f; }

  for (int i0 = 0; i0 < 192; i0 += 4) {
    *(float2*)(xl + xr_row * 256 + xr_col) = xr;
    __syncthreads();
    if (i0 + 4 < 192) {
      int i = i0 + 4;
      xr = *(const float2*)(srcs[i >> 6] + (size_t)(b * 64 + ((i + xr_row) & 63)) * NPIX + n0 + xr_col);
    }
    float4 x0 = *(const float4*)(xl + 0 * 256 + lane * 4);
    float4 x1 = *(const float4*)(xl + 1 * 256 + lane * 4);
    float4 x2 = *(const float4*)(xl + 2 * 256 + lane * 4);
    float4 x3 = *(const float4*)(xl + 3 * 256 + lane * 4);
#pragma unroll
    for (int c8 = 0; c8 < 8; ++c8) {
      float4 m = *(const float4*)(Ml + (w * 8 + c8) * 192 + i0);
      acc[c8].x = fmaf(m.x, x0.x, fmaf(m.y, x1.x, fmaf(m.z, x2.x, fmaf(m.w, x3.x, acc[c8].x))));
      acc[c8].y = fmaf(m.x, x0.y, fmaf(m.y, x1.y, fmaf(m.z, x2.y, fmaf(m.w, x3.y, acc[c8].y))));
      acc[c8].z = fmaf(m.x, x0.z, fmaf(m.y, x1.z, fmaf(m.z, x2.z, fmaf(m.w, x3.z, acc[c8].z))));
      acc[c8].w = fmaf(m.x, x0.w, fmaf(m.y, x1.w, fmaf(m.z, x2.w, fmaf(m.w, x3.w, acc[c8].w))));
    }
    __syncthreads();
  }
#pragma unroll
  for (int c8 = 0; c8 < 8; ++c8) {
    int c = w * 8 + c8;
    float4 o;
    o.x = acc[c8].x + c0l[c];
    o.y = acc[c8].y + c0l[c];
    o.z = acc[c8].z + c0l[c];
    o.w = acc[c8].w + c0l[c];
    *(float4*)(out + (size_t)(b * 64 + c) * NPIX + n0 + lane * 4) = o;
  }
}

extern "C" void kernel_launch(void* const* d_in, const int* in_sizes, int n_in,
                              void* d_out, int out_size, void* d_ws, size_t ws_size,
                              hipStream_t stream) {
  const float* rgb = (const float*)d_in[0];
  const float* hsv = (const float*)d_in[1];
  const float* lab = (const float*)d_in[2];
  const float* Wq = (const float*)d_in[3];
  const float* bq = (const float*)d_in[4];
  const float* Wk = (const float*)d_in[5];
  const float* bk = (const float*)d_in[6];
  const float* Wv = (const float*)d_in[7];
  const float* bv = (const float*)d_in[8];
  float* out = (float*)d_out;
  float* ws = (float*)d_ws;

  float* G = ws;                  // 4*192*192 = 147456 f32
  float* S = ws + 147456;         // 4*192     = 768
  float* Mw = ws + 148224;        // 4*64*192  = 49152
  float* c0w = ws + 197376;       // 4*64      = 256
  float* part = ws + 197632;      // 256*37056 = 9486336 (optional partials)
  const int use_part =
      (ws_size >= (size_t)(197632 + 9486336) * sizeof(float)) ? 1 : 0;

  if (!use_part)
    k0_zero<<<dim3(579), dim3(256), 0, stream>>>(ws, 148224);  // zero G + S
  k1_gram<<<dim3(64, 4), dim3(768), 0, stream>>>(rgb, hsv, lab, G, S, part, use_part);
  if (use_part)
    k1r_reduce<<<dim3(579), dim3(256), 0, stream>>>(part, G, S);
  k2_small<<<dim3(8, 4), dim3(256), 0, stream>>>(G, S, Wq, bq, Wk, bk, Wv, bv, Mw, c0w);
  k3_out<<<dim3(256, 4), dim3(512), 0, stream>>>(rgb, hsv, lab, Mw, c0w, out);
}

// Round 3
// 147.942 us; speedup vs baseline: 3.8542x; 1.4010x over previous
//
#include <hip/hip_runtime.h>
#include <cstddef>

// CAM module, algebraically restructured:
//   X = concat(rgb,hsv,lab) : [B=4, 192, N=65536] (f32)
//   G[b] = X X^T (192x192), s[b] = row sums        (K1, fp16 MFMA, 2-deep prefetch)
//   energy = (Wq G Wk^T + bq sk^T + sq bk^T + N bq bk^T)/8 ; att = softmax_d
//   M = att Wv (emitted as swizzled fp16) ; c0 = att bv   (K2, f32)
//   out = M X + c0                                  (K3, fp16 MFMA, memory-bound)

#define NPIX 65536

typedef _Float16 half4_t __attribute__((ext_vector_type(4)));
typedef _Float16 half8_t __attribute__((ext_vector_type(8)));
typedef float f32x4_t __attribute__((ext_vector_type(4)));

// ---------------- K0: zero G+S (atomic-fallback path only) ----------------
__global__ void k0_zero(float* __restrict__ p, int n) {
  int i = blockIdx.x * 256 + threadIdx.x;
  if (i < n) p[i] = 0.0f;
}

// ---------------- K1: Gram + row sums ----------------
// grid (64, 4), block 768 (12 waves as 2x6). 1024 cols/block, 16 chunks of 64.
// 2-deep register prefetch (A=chunk c, B=chunk c+1; load c+2 during compute c).
__global__ __launch_bounds__(768, 3) void k1_gram(
    const float* __restrict__ rgb, const float* __restrict__ hsv, const float* __restrict__ lab,
    float* __restrict__ G, float* __restrict__ S, float* __restrict__ part, int use_part) {
  __shared__ alignas(16) unsigned char smem[24576];
  _Float16* lds = (_Float16*)smem;
  float* slds = (float*)smem;

  const int t = threadIdx.x;
  const int lane = t & 63;
  const int w = t >> 6;          // 0..11
  const int wi = w & 1;          // 0..1
  const int wj = w >> 1;         // 0..5
  const int b = blockIdx.y;
  const int n0 = blockIdx.x * 1024;

  const int row = t >> 2;        // 0..191
  const int cq = (t & 3) << 4;   // 0,16,32,48
  const float* srcs[3] = {rgb, hsv, lab};
  const float* gp = srcs[row >> 6] + (size_t)(b * 64 + (row & 63)) * NPIX + n0 + cq;

  f32x4_t acc[6][2];
  const f32x4_t zero4 = {0.0f, 0.0f, 0.0f, 0.0f};
#pragma unroll
  for (int a = 0; a < 6; ++a)
#pragma unroll
    for (int j = 0; j < 2; ++j) acc[a][j] = zero4;
  float s_acc = 0.0f;

  const int sw = (row & 7) << 3;   // swizzle (fp16 units)
  const int rbase = row * 64;

  float4 A0, A1, A2, A3, B0, B1, B2, B3;
  auto loadA = [&](int cc) {
    const float* p = gp + cc * 64;
    A0 = *(const float4*)(p + 0); A1 = *(const float4*)(p + 4);
    A2 = *(const float4*)(p + 8); A3 = *(const float4*)(p + 12);
  };
  auto loadB = [&](int cc) {
    const float* p = gp + cc * 64;
    B0 = *(const float4*)(p + 0); B1 = *(const float4*)(p + 4);
    B2 = *(const float4*)(p + 8); B3 = *(const float4*)(p + 12);
  };
  auto writeLDS = [&](float4 r0, float4 r1, float4 r2, float4 r3) {
    s_acc += (r0.x + r0.y + r0.z + r0.w) + (r1.x + r1.y + r1.z + r1.w) +
             (r2.x + r2.y + r2.z + r2.w) + (r3.x + r3.y + r3.z + r3.w);
    half4_t h;
    h.x = (_Float16)r0.x; h.y = (_Float16)r0.y; h.z = (_Float16)r0.z; h.w = (_Float16)r0.w;
    *(half4_t*)(lds + rbase + ((cq + 0) ^ sw)) = h;
    h.x = (_Float16)r1.x; h.y = (_Float16)r1.y; h.z = (_Float16)r1.z; h.w = (_Float16)r1.w;
    *(half4_t*)(lds + rbase + ((cq + 4) ^ sw)) = h;
    h.x = (_Float16)r2.x; h.y = (_Float16)r2.y; h.z = (_Float16)r2.z; h.w = (_Float16)r2.w;
    *(half4_t*)(lds + rbase + ((cq + 8) ^ sw)) = h;
    h.x = (_Float16)r3.x; h.y = (_Float16)r3.y; h.z = (_Float16)r3.z; h.w = (_Float16)r3.w;
    *(half4_t*)(lds + rbase + ((cq + 12) ^ sw)) = h;
  };
  auto compute = [&]() {
#pragma unroll
    for (int ks = 0; ks < 2; ++ks) {
      const int kc = ks * 32 + 8 * (lane >> 4);
      half8_t fA[6], fB[2];
#pragma unroll
      for (int a = 0; a < 6; ++a) {
        int rA = wi * 96 + a * 16 + (lane & 15);
        fA[a] = *(const half8_t*)(lds + rA * 64 + (kc ^ ((rA & 7) << 3)));
      }
#pragma unroll
      for (int j = 0; j < 2; ++j) {
        int rB = (wj * 2 + j) * 16 + (lane & 15);
        fB[j] = *(const half8_t*)(lds + rB * 64 + (kc ^ ((rB & 7) << 3)));
      }
#pragma unroll
      for (int a = 0; a < 6; ++a)
#pragma unroll
        for (int j = 0; j < 2; ++j)
          acc[a][j] = __builtin_amdgcn_mfma_f32_16x16x32_f16(fA[a], fB[j], acc[a][j], 0, 0, 0);
    }
  };

  loadA(0);
  loadB(1);
  for (int cc = 0; cc < 16; cc += 2) {
    writeLDS(A0, A1, A2, A3);
    __syncthreads();
    if (cc + 2 < 16) loadA(cc + 2);
    compute();
    __syncthreads();
    writeLDS(B0, B1, B2, B3);
    __syncthreads();
    if (cc + 3 < 16) loadB(cc + 3);
    compute();
    __syncthreads();
  }

  // ---- flush Gram ----
  if (use_part) {
    float* pb = part + (size_t)(b * 64 + blockIdx.x) * 37056;
#pragma unroll
    for (int a = 0; a < 6; ++a)
#pragma unroll
      for (int j = 0; j < 2; ++j) {
        int tt = (wi * 6 + a) * 12 + (wj * 2 + j);
        *(f32x4_t*)(pb + tt * 256 + lane * 4) = acc[a][j];
      }
  } else {
    float* Gb = G + b * 36864;
#pragma unroll
    for (int a = 0; a < 6; ++a)
#pragma unroll
      for (int j = 0; j < 2; ++j) {
        int I = wi * 6 + a, J = wj * 2 + j;
#pragma unroll
        for (int r = 0; r < 4; ++r) {
          int gr = I * 16 + ((lane >> 4) << 2) + r;
          int gc = J * 16 + (lane & 15);
          atomicAdd(Gb + gr * 192 + gc, acc[a][j][r]);
        }
      }
  }

  // ---- row sums ----
  slds[t] = s_acc;
  __syncthreads();
  if (t < 192) {
    float s = (slds[t * 4] + slds[t * 4 + 1]) + (slds[t * 4 + 2] + slds[t * 4 + 3]);
    if (use_part)
      part[(size_t)(b * 64 + blockIdx.x) * 37056 + 36864 + t] = s;
    else
      atomicAdd(S + b * 192 + t, s);
  }
}

// ---------------- K1.5: deterministic reduce of 64 partials ----------------
__global__ void k1r_reduce(const float* __restrict__ part, float* __restrict__ G,
                           float* __restrict__ S) {
  int idx = blockIdx.x * 256 + threadIdx.x;
  if (idx >= 4 * 37056) return;
  int b = idx / 37056;
  int flat = idx % 37056;
  const float* base = part + (size_t)b * 64 * 37056 + flat;
  float v0 = 0.f, v1 = 0.f, v2 = 0.f, v3 = 0.f;
#pragma unroll
  for (int q = 0; q < 64; q += 4) {
    v0 += base[(size_t)(q + 0) * 37056];
    v1 += base[(size_t)(q + 1) * 37056];
    v2 += base[(size_t)(q + 2) * 37056];
    v3 += base[(size_t)(q + 3) * 37056];
  }
  float v = (v0 + v1) + (v2 + v3);
  if (flat < 36864) {
    int tt = flat >> 8;
    int I = tt / 12, J = tt % 12;
    int r = flat & 255;
    int lane = r >> 2, rg = r & 3;
    int row = I * 16 + ((lane >> 4) << 2) + rg;
    int col = J * 16 + (lane & 15);
    G[b * 36864 + row * 192 + col] = v;
  } else {
    S[b * 192 + (flat - 36864)] = v;
  }
}

// ---------------- K2: energy -> softmax -> M(fp16 swizzled), c0 ----------------
__global__ __launch_bounds__(256) void k2_small(
    const float* __restrict__ G, const float* __restrict__ S,
    const float* __restrict__ Wq, const float* __restrict__ bq,
    const float* __restrict__ Wk, const float* __restrict__ bk,
    const float* __restrict__ Wv, const float* __restrict__ bv,
    _Float16* __restrict__ Mh, float* __restrict__ c0w) {
  const int b = blockIdx.y;
  const int cbase = blockIdx.x * 8;
  const int t = threadIdx.x;
  __shared__ float T1[192 * 9];
  __shared__ float el[64 * 8];
  __shared__ float sq[8];
  __shared__ float sk[64];
  const float* Gb = G + b * 36864;
  const float* Sb = S + b * 192;

  if (t < 8) {
    float a = 0.f;
    const float* wq = Wq + (cbase + t) * 192;
    for (int i = 0; i < 192; ++i) a = fmaf(wq[i], Sb[i], a);
    sq[t] = a;
  } else if (t < 72) {
    int d = t - 8;
    float a = 0.f;
    const float* wk = Wk + d * 192;
    for (int j = 0; j < 192; ++j) a = fmaf(wk[j], Sb[j], a);
    sk[d] = a;
  }
  for (int e = t; e < 1536; e += 256) {
    int j = e % 192, cp = e / 192;
    const float* wq = Wq + (cbase + cp) * 192;
    float a = 0.f;
    for (int i = 0; i < 192; ++i) a = fmaf(wq[i], Gb[i * 192 + j], a);
    T1[j * 9 + cp] = a;
  }
  __syncthreads();
  for (int e = t; e < 512; e += 256) {
    int cp = e & 7, d = e >> 3;
    const float* wk = Wk + d * 192;
    float a = 0.f;
    for (int j = 0; j < 192; ++j) a = fmaf(T1[j * 9 + cp], wk[j], a);
    float bqc = bq[cbase + cp], bkd = bk[d];
    a += bqc * sk[d] + bkd * sq[cp] + 65536.0f * bqc * bkd;
    el[d * 8 + cp] = a * 0.125f;
  }
  __syncthreads();
  if (t < 8) {
    float mx = -3.0e38f;
    for (int d = 0; d < 64; ++d) mx = fmaxf(mx, el[d * 8 + t]);
    float sum = 0.f;
    for (int d = 0; d < 64; ++d) {
      float pv = expf(el[d * 8 + t] - mx);
      el[d * 8 + t] = pv;
      sum += pv;
    }
    float inv = 1.0f / sum;
    for (int d = 0; d < 64; ++d) el[d * 8 + t] *= inv;
  }
  __syncthreads();
  // M rows in fp16, swizzled exactly as K3's lds_m image: idx = c*192 + (i ^ ((c&7)<<3))
  for (int e = t; e < 1536; e += 256) {
    int i = e % 192, cp = e / 192;
    int c = cbase + cp;
    float a = 0.f;
    for (int d = 0; d < 64; ++d) a = fmaf(el[d * 8 + cp], Wv[d * 192 + i], a);
    Mh[(size_t)b * 12288 + c * 192 + (i ^ ((c & 7) << 3))] = (_Float16)a;
  }
  if (t < 8) {
    float a = 0.f;
    for (int d = 0; d < 64; ++d) a = fmaf(el[d * 8 + t], bv[d], a);
    c0w[b * 64 + cbase + t] = a;
  }
}

// ---------------- K3: out = M X + c0 (fp16 MFMA) ----------------
// grid (256, 4), block 256 (4 waves). Block: C[64 x 256n]; wave w: n-span w*64.
// X chunk [32 i][256 n] staged transposed into lds_x[n][32] fp16, swizzle i^=(n&3)<<3.
// M staged once (linear copy of pre-swizzled fp16 image). acc[4][4] = 64 VGPR.
__global__ __launch_bounds__(256, 3) void k3_out(
    const float* __restrict__ rgb, const float* __restrict__ hsv, const float* __restrict__ lab,
    const _Float16* __restrict__ Mh, const float* __restrict__ c0w, float* __restrict__ out) {
  __shared__ alignas(16) _Float16 lds_m[12288];
  __shared__ alignas(16) _Float16 lds_x[8192];
  __shared__ float c0l[64];
  const int t = threadIdx.x;
  const int lane = t & 63;
  const int w = t >> 6;
  const int b = blockIdx.y;
  const int nblk = blockIdx.x * 256;

  {  // stage M (24576 B) as 16B copies + c0
    const float4* msrc = (const float4*)(Mh + (size_t)b * 12288);
    float4* mdst = (float4*)lds_m;
#pragma unroll
    for (int k = 0; k < 6; ++k) mdst[t + 256 * k] = msrc[t + 256 * k];
    if (t < 64) c0l[t] = c0w[b * 64 + t];
  }

  const int xi = t & 31;   // i within chunk
  const int ng = t >> 5;   // 0..7: n-group of 32
  const float* srcs[3] = {rgb, hsv, lab};

  f32x4_t acc[4][4];
  const f32x4_t zero4 = {0.0f, 0.0f, 0.0f, 0.0f};
#pragma unroll
  for (int i = 0; i < 4; ++i)
#pragma unroll
    for (int j = 0; j < 4; ++j) acc[i][j] = zero4;

  float4 xr[8];
  auto xload = [&](int kc) {
    int ig = kc * 32 + xi;
    const float* p = srcs[ig >> 6] + (size_t)(b * 64 + (ig & 63)) * NPIX + nblk + ng * 32;
#pragma unroll
    for (int f = 0; f < 8; ++f) xr[f] = *(const float4*)(p + f * 4);
  };
  auto xwrite = [&]() {
#pragma unroll
    for (int f = 0; f < 8; ++f) {
      int n = ng * 32 + f * 4;
      lds_x[(n + 0) * 32 + (xi ^ 0)]  = (_Float16)xr[f].x;
      lds_x[(n + 1) * 32 + (xi ^ 8)]  = (_Float16)xr[f].y;
      lds_x[(n + 2) * 32 + (xi ^ 16)] = (_Float16)xr[f].z;
      lds_x[(n + 3) * 32 + (xi ^ 24)] = (_Float16)xr[f].w;
    }
  };

  const int g = lane >> 4;     // 0..3
  const int l15 = lane & 15;

  xload(0);
  for (int kc = 0; kc < 6; ++kc) {
    xwrite();
    __syncthreads();
    if (kc + 1 < 6) xload(kc + 1);
    half8_t fx[4], fm[4];
#pragma unroll
    for (int nt = 0; nt < 4; ++nt) {
      int n = w * 64 + nt * 16 + l15;
      fx[nt] = *(const half8_t*)(lds_x + n * 32 + ((8 * g) ^ ((n & 3) << 3)));
    }
#pragma unroll
    for (int ct = 0; ct < 4; ++ct) {
      int c = ct * 16 + l15;
      fm[ct] = *(const half8_t*)(lds_m + c * 192 + ((kc * 32 + 8 * g) ^ ((c & 7) << 3)));
    }
#pragma unroll
    for (int nt = 0; nt < 4; ++nt)
#pragma unroll
      for (int ct = 0; ct < 4; ++ct)
        acc[nt][ct] = __builtin_amdgcn_mfma_f32_16x16x32_f16(fx[nt], fm[ct], acc[nt][ct], 0, 0, 0);
    __syncthreads();
  }

  // epilogue: C-row (n) = 4*g + r from first operand, C-col (c) = l15 from second
#pragma unroll
  for (int ct = 0; ct < 4; ++ct) {
    int c = ct * 16 + l15;
    float c0v = c0l[c];
#pragma unroll
    for (int nt = 0; nt < 4; ++nt) {
      int n = nblk + w * 64 + nt * 16 + 4 * g;
      float4 o;
      o.x = acc[nt][ct][0] + c0v;
      o.y = acc[nt][ct][1] + c0v;
      o.z = acc[nt][ct][2] + c0v;
      o.w = acc[nt][ct][3] + c0v;
      *(float4*)(out + (size_t)(b * 64 + c) * NPIX + n) = o;
    }
  }
}

extern "C" void kernel_launch(void* const* d_in, const int* in_sizes, int n_in,
                              void* d_out, int out_size, void* d_ws, size_t ws_size,
                              hipStream_t stream) {
  const float* rgb = (const float*)d_in[0];
  const float* hsv = (const float*)d_in[1];
  const float* lab = (const float*)d_in[2];
  const float* Wq = (const float*)d_in[3];
  const float* bq = (const float*)d_in[4];
  const float* Wk = (const float*)d_in[5];
  const float* bk = (const float*)d_in[6];
  const float* Wv = (const float*)d_in[7];
  const float* bv = (const float*)d_in[8];
  float* out = (float*)d_out;
  float* ws = (float*)d_ws;

  float* G = ws;                        // 147456 f32
  float* S = ws + 147456;               // 768
  _Float16* Mh = (_Float16*)(ws + 148224);  // 49152 halves = 24576 f32 slots
  float* c0w = ws + 172800;             // 256
  float* part = ws + 173056;            // 9486336 (optional partials)
  const int use_part =
      (ws_size >= (size_t)(173056 + 9486336) * sizeof(float)) ? 1 : 0;

  if (!use_part)
    k0_zero<<<dim3(579), dim3(256), 0, stream>>>(ws, 148224);  // zero G + S
  k1_gram<<<dim3(64, 4), dim3(768), 0, stream>>>(rgb, hsv, lab, G, S, part, use_part);
  if (use_part)
    k1r_reduce<<<dim3(579), dim3(256), 0, stream>>>(part, G, S);
  k2_small<<<dim3(8, 4), dim3(256), 0, stream>>>(G, S, Wq, bq, Wk, bk, Wv, bv, Mh, c0w);
  k3_out<<<dim3(256, 4), dim3(256), 0, stream>>>(rgb, hsv, lab, Mh, c0w, out);
}